// Round 9
// baseline (304.073 us; speedup 1.0000x reference)
//
#include <hip/hip_runtime.h>
#include <hip/hip_bf16.h>
#include <float.h>

typedef _Float16 f16;
typedef __attribute__((ext_vector_type(8))) _Float16 half8;
typedef __attribute__((ext_vector_type(4))) float floatx4;

// Problem constants
#define DIM   128
#define HW    4096
#define NPOS  131072
#define K     512
#define ZSTRIDE_B 524288

// Output layout (floats)
#define Q_OFF     0
#define LOSS_OFF  16777216
#define IDX_OFF   16777217
#define NEMB_OFF  16908289
#define NCS_OFF   16973825
#define NEA_OFF   16974337

// Workspace layout (floats). e_hiP/e_loP OVERLAY the esum region: k_prep writes
// them, k_assign reads them, then esum is memset to 0 before k_ema2 uses it.
#define WS_E2    0
#define WS_ENC   512
#define WS_ESUM  1024
#define WS_EHI   1024          // f16[K*DIM] = 32768 floats
#define WS_ELO   33792         // f16[K*DIM] = 32768 floats (ends at 66560)
#define WS_LOSS  66560
#define WS_NN    66561

#define XST 136   // xs row stride (f16): 128 d + 8 pad -> 272B, 16B-aligned, 2-way banks

// ---------------------------------------------------------------------------
// k_prep: split codebook into f16 hi/lo in a FRAGMENT-LINEAR packed layout:
//   element e[c][dd]: g = c>>4, r = c&15, dc = dd>>5, quad = (dd>>3)&3, j = dd&7
//   packed[(g*4+dc)*512 + quad*128 + r*8 + j]
// Property 1: B-fragment load for a 16x16 MFMA tile = 64 lanes x 16B CONTIGUOUS.
// Property 2: for fixed code c and d-octet o, the 8 values are ONE contiguous
//             16B half8 at (g*4+(o>>2))*512 + (o&3)*128 + r*8  (Q-gather path).
__global__ __launch_bounds__(256) void k_prep(const float* __restrict__ emb,
                                              f16* __restrict__ ehiP,
                                              f16* __restrict__ eloP,
                                              float* __restrict__ e2) {
    int lin = blockIdx.x * 256 + threadIdx.x;   // 65536 threads
    int d = lin >> 9, k = lin & 511;
    float v = emb[lin];                          // coalesced read
    unsafeAtomicAdd(&e2[k], v * v);              // native fp32 atomic
    f16 h = (f16)v;
    f16 l = (f16)(v - (float)h);
    int g = k >> 4, r = k & 15;
    int dc = d >> 5, w = d & 31, quad = w >> 3, j = w & 7;
    int idx = (g * 4 + dc) * 512 + quad * 128 + r * 8 + j;
    ehiP[idx] = h;                               // scattered 2B writes (one-shot, tiny)
    eloP[idx] = l;
}

// ---------------------------------------------------------------------------
// k_assign (MFMA): 64 positions/block, all 512 codes, D=128.
// score = e2[c] - 2*dot(x,e); dot via 3-pass f16-split MFMA (hh + lh + hl).
// 4 code-chunks of 128 (acc[4][2] = 32 VGPR), (256,2) pin.
// Q-output + loss epilogue via the PACKED f16 codebook (16B half8 gathers).
__global__ __launch_bounds__(256, 2) void k_assign(const float* __restrict__ z,
                                                   const f16* __restrict__ ehiP,
                                                   const f16* __restrict__ eloP,
                                                   const float* __restrict__ e2,
                                                   float* __restrict__ out,
                                                   float* __restrict__ lossAcc) {
    __shared__ f16 xs_h[64 * XST];
    __shared__ f16 xs_l[64 * XST];
    __shared__ float wbD[256];
    __shared__ int   wbI[256];
    __shared__ int   bidx[64];
    __shared__ float wred[4];

    const int tid  = threadIdx.x;
    const int lane = tid & 63;
    const int wv   = tid >> 6;
    const int n0   = blockIdx.x * 64;
    const int b    = n0 >> 12;
    const int hw0  = n0 & 4095;
    const float* zb = z + b * ZSTRIDE_B + hw0;
    const int l15  = lane & 15;
    const int quad = lane >> 4;

    // ---- stage X split (64 pos x 128 d): phase 1 = issue all 32 loads,
    // phase 2 = convert + packed u32 LDS writes. Static indexing throughout.
    float sv0[16], sv1[16];
    #pragma unroll
    for (int it = 0; it < 16; ++it) {
        int lin = tid + it * 256;
        int i  = lin & 63;          // position (lanes consecutive -> coalesced)
        int dp = lin >> 6;          // d-pair 0..63
        sv0[it] = zb[(2 * dp) * HW + i];
        sv1[it] = zb[(2 * dp + 1) * HW + i];
    }
    #pragma unroll
    for (int it = 0; it < 16; ++it) {
        int lin = tid + it * 256;
        int i  = lin & 63;
        int dp = lin >> 6;
        float v0 = sv0[it], v1 = sv1[it];
        f16 h0 = (f16)v0; f16 l0 = (f16)(v0 - (float)h0);
        f16 h1 = (f16)v1; f16 l1 = (f16)(v1 - (float)h1);
        union { f16 h[2]; unsigned int u; } ph, pl;
        ph.h[0] = h0; ph.h[1] = h1;
        pl.h[0] = l0; pl.h[1] = l1;
        *(unsigned int*)&xs_h[i * XST + 2 * dp] = ph.u;
        *(unsigned int*)&xs_l[i * XST + 2 * dp] = pl.u;
    }
    __syncthreads();

    float bestD[4][4];
    int   bestI[4][4];
    #pragma unroll
    for (int t = 0; t < 4; ++t)
        #pragma unroll
        for (int r = 0; r < 4; ++r) { bestD[t][r] = FLT_MAX; bestI[t][r] = 0x7fffffff; }

    const half8* gh = (const half8*)ehiP;
    const half8* gl = (const half8*)eloP;

    for (int cc = 0; cc < 4; ++cc) {       // 4 chunks x 128 codes
        floatx4 acc[4][2];
        #pragma unroll
        for (int t = 0; t < 4; ++t)
            #pragma unroll
            for (int nt = 0; nt < 2; ++nt) acc[t][nt] = (floatx4){0.f, 0.f, 0.f, 0.f};

        for (int dc = 0; dc < 4; ++dc) {
            // A fragments: A[m = t*16 + (lane&15)][k = quad*8 + j]
            half8 ah[4], al[4];
            #pragma unroll
            for (int t = 0; t < 4; ++t) {
                int off = (t * 16 + l15) * XST + dc * 32 + quad * 8;
                ah[t] = *(const half8*)&xs_h[off];
                al[t] = *(const half8*)&xs_l[off];
            }
            #pragma unroll
            for (int nt = 0; nt < 2; ++nt) {
                // B fragment: wave-contiguous 1KB load from packed codebook
                int g  = cc * 8 + wv * 2 + nt;      // 16-code group
                int bi = (g * 4 + dc) * 64 + lane;
                half8 bh = gh[bi];
                half8 bl = gl[bi];
                #pragma unroll
                for (int t = 0; t < 4; ++t) {
                    acc[t][nt] = __builtin_amdgcn_mfma_f32_16x16x32_f16(ah[t], bh, acc[t][nt], 0, 0, 0);
                    acc[t][nt] = __builtin_amdgcn_mfma_f32_16x16x32_f16(al[t], bh, acc[t][nt], 0, 0, 0);
                    acc[t][nt] = __builtin_amdgcn_mfma_f32_16x16x32_f16(ah[t], bl, acc[t][nt], 0, 0, 0);
                }
            }
        }
        // fold scores into best (codes ascend across cc,nt for fixed lane -> strict <)
        #pragma unroll
        for (int nt = 0; nt < 2; ++nt) {
            int c = cc * 128 + wv * 32 + nt * 16 + l15;
            float ee = e2[c];
            #pragma unroll
            for (int t = 0; t < 4; ++t)
                #pragma unroll
                for (int r = 0; r < 4; ++r) {
                    float s = fmaf(-2.f, acc[t][nt][r], ee);
                    if (s < bestD[t][r]) { bestD[t][r] = s; bestI[t][r] = c; }
                }
        }
    }

    // reduce across the 16 lanes holding different codes for the same rows
    #pragma unroll
    for (int mask = 1; mask <= 8; mask <<= 1) {
        #pragma unroll
        for (int t = 0; t < 4; ++t)
            #pragma unroll
            for (int r = 0; r < 4; ++r) {
                float od = __shfl_xor(bestD[t][r], mask, 64);
                int   oi = __shfl_xor(bestI[t][r], mask, 64);
                if (od < bestD[t][r] || (od == bestD[t][r] && oi < bestI[t][r])) {
                    bestD[t][r] = od; bestI[t][r] = oi;
                }
            }
    }
    if (l15 == 0) {
        #pragma unroll
        for (int t = 0; t < 4; ++t)
            #pragma unroll
            for (int r = 0; r < 4; ++r) {
                int m = t * 16 + quad * 4 + r;   // C layout: row=(lane>>4)*4+reg
                wbD[wv * 64 + m] = bestD[t][r];
                wbI[wv * 64 + m] = bestI[t][r];
            }
    }
    __syncthreads();
    if (tid < 64) {
        float bd = wbD[tid]; int bi = wbI[tid];
        #pragma unroll
        for (int w = 1; w < 4; ++w) {
            float od = wbD[w * 64 + tid]; int oi = wbI[w * 64 + tid];
            if (od < bd || (od == bd && oi < bi)) { bd = od; bi = oi; }
        }
        bidx[tid] = bi;
        out[IDX_OFF + n0 + tid] = (float)bi;
    }
    __syncthreads();

    // ---- epilogue: Q gather from PACKED f16 codebook (16B loads) + loss.
    float* qb = out + Q_OFF + b * ZSTRIDE_B + hw0;
    float lsum = 0.f;
    #pragma unroll
    for (int it = 0; it < 4; ++it) {
        int o = wv * 4 + it;
        int c = bidx[lane];
        int g = c >> 4, r = c & 15;
        int base = (g * 4 + (o >> 2)) * 512 + (o & 3) * 128 + r * 8;
        half8 hh = *(const half8*)&ehiP[base];   // 16B random L2 load
        half8 ll = *(const half8*)&eloP[base];
        half8 zh = *(const half8*)&xs_h[lane * XST + o * 8];
        half8 zl = *(const half8*)&xs_l[lane * XST + o * 8];
        #pragma unroll
        for (int jj = 0; jj < 8; ++jj) {
            float q  = (float)hh[jj] + (float)ll[jj];
            float zz = (float)zh[jj] + (float)zl[jj];
            qb[(o * 8 + jj) * HW + lane] = q;    // lanes consecutive: 256B coalesced
            float df = q - zz;
            lsum = fmaf(df, df, lsum);
        }
    }
    #pragma unroll
    for (int m = 32; m >= 1; m >>= 1) lsum += __shfl_xor(lsum, m, 64);
    if (lane == 0) wred[wv] = lsum;
    __syncthreads();
    if (tid == 0) unsafeAtomicAdd(lossAcc, wred[0] + wred[1] + wred[2] + wred[3]);
}

// ---------------------------------------------------------------------------
// k_ema2 v9: segment-sum as ONE-HOT MFMA GEMM -- zero LDS atomics in the hot
// path. Evidence (r5-r8): the atomicAdd segment-sum was ~100us invariant to
// atomic flavor/spread/blocks with ALL pipes idle => LDS-atomic unit
// serializes per-lane (~16.8M lane-ops). Replacement:
//   esum[d,k] = sum_p z[d,p] * onehot(idx[p]==k)   (B exact in f16!)
// Block = (b, dchunk of 16 d's, half of 2048 pos); 4 waves x 512 pos each.
// Per 32-pos tile: build one-hot B frags in regs (static idx only, rule #20),
// 2 MFMAs (z-hi, z-lo) per nonempty 16-code tile, wave-uniform branch skip.
// Epilogue: 4-round cross-wave LDS reduce (plain writes) + coalesced
// unsafeAtomicAdd flush. cnt via tiny u32 LDS histogram (1/128 the lane-ops).
__global__ __launch_bounds__(256) void k_ema2(const float* __restrict__ z,
                                              const float* __restrict__ out,
                                              float* __restrict__ enc,
                                              float* __restrict__ esum) {
    __shared__ float red[16 * K];        // 32 KB
    __shared__ unsigned int hist[K];     // 2 KB

    const int tid  = threadIdx.x;
    const int lane = tid & 63;
    const int wv   = tid >> 6;
    const int l15  = lane & 15;
    const int quad = lane >> 4;
    const int half   = blockIdx.x & 1;
    const int dchunk = (blockIdx.x >> 1) & 7;
    const int b      = blockIdx.x >> 4;
    const int d0 = dchunk * 16;
    const bool doCnt = (dchunk == 0);

    if (doCnt) { hist[tid] = 0u; hist[tid + 256] = 0u; }
    __syncthreads();

    const float* idp = out + IDX_OFF + b * HW;
    const float* zrow = z + b * ZSTRIDE_B + (d0 + l15) * HW;

    floatx4 acc[32];
    #pragma unroll
    for (int t = 0; t < 32; ++t) acc[t] = (floatx4){0.f, 0.f, 0.f, 0.f};

    const int p_base = half * 2048 + wv * 512;
    for (int pt = 0; pt < 16; ++pt) {
        const int p0 = p_base + pt * 32;
        // this lane's 8 position indices (same within a quad -> broadcast loads)
        float4 iva = *(const float4*)(idp + p0 + quad * 8);
        float4 ivb = *(const float4*)(idp + p0 + quad * 8 + 4);
        int v0 = (int)iva.x, v1 = (int)iva.y, v2 = (int)iva.z, v3 = (int)iva.w;
        int v4 = (int)ivb.x, v5 = (int)ivb.y, v6 = (int)ivb.z, v7 = (int)ivb.w;
        // nonempty 16-code-tile mask (wave-uniform after OR-reduce)
        unsigned int m = (1u << (v0 >> 4)) | (1u << (v1 >> 4)) |
                         (1u << (v2 >> 4)) | (1u << (v3 >> 4)) |
                         (1u << (v4 >> 4)) | (1u << (v5 >> 4)) |
                         (1u << (v6 >> 4)) | (1u << (v7 >> 4));
        m |= __shfl_xor(m, 16, 64);
        m |= __shfl_xor(m, 32, 64);
        // A fragments: z[d0+l15][p0 + quad*8 + j], f16 hi/lo split
        float4 za = *(const float4*)(zrow + p0 + quad * 8);
        float4 zb4 = *(const float4*)(zrow + p0 + quad * 8 + 4);
        half8 ah, al;
        {
            float v;
            v = za.x;  ah[0] = (f16)v; al[0] = (f16)(v - (float)ah[0]);
            v = za.y;  ah[1] = (f16)v; al[1] = (f16)(v - (float)ah[1]);
            v = za.z;  ah[2] = (f16)v; al[2] = (f16)(v - (float)ah[2]);
            v = za.w;  ah[3] = (f16)v; al[3] = (f16)(v - (float)ah[3]);
            v = zb4.x; ah[4] = (f16)v; al[4] = (f16)(v - (float)ah[4]);
            v = zb4.y; ah[5] = (f16)v; al[5] = (f16)(v - (float)ah[5]);
            v = zb4.z; ah[6] = (f16)v; al[6] = (f16)(v - (float)ah[6]);
            v = zb4.w; ah[7] = (f16)v; al[7] = (f16)(v - (float)ah[7]);
        }
        #pragma unroll
        for (int t = 0; t < 32; ++t) {
            if (m & (1u << t)) {
                const int target = t * 16 + l15;
                half8 bh;
                bh[0] = (v0 == target) ? (f16)1 : (f16)0;
                bh[1] = (v1 == target) ? (f16)1 : (f16)0;
                bh[2] = (v2 == target) ? (f16)1 : (f16)0;
                bh[3] = (v3 == target) ? (f16)1 : (f16)0;
                bh[4] = (v4 == target) ? (f16)1 : (f16)0;
                bh[5] = (v5 == target) ? (f16)1 : (f16)0;
                bh[6] = (v6 == target) ? (f16)1 : (f16)0;
                bh[7] = (v7 == target) ? (f16)1 : (f16)0;
                acc[t] = __builtin_amdgcn_mfma_f32_16x16x32_f16(ah, bh, acc[t], 0, 0, 0);
                acc[t] = __builtin_amdgcn_mfma_f32_16x16x32_f16(al, bh, acc[t], 0, 0, 0);
            }
        }
    }

    // cnt histogram (u32 LDS atomics, 8 positions/thread, doCnt blocks only)
    if (doCnt) {
        const int hp = half * 2048 + tid * 8;
        #pragma unroll
        for (int j = 0; j < 2; ++j) {
            float4 iv = *(const float4*)(idp + hp + 4 * j);
            atomicAdd(&hist[(int)iv.x], 1u);
            atomicAdd(&hist[(int)iv.y], 1u);
            atomicAdd(&hist[(int)iv.z], 1u);
            atomicAdd(&hist[(int)iv.w], 1u);
        }
    }

    // cross-wave reduce: D[row=quad*4+r][col=t*16+l15], plain LDS writes,
    // sequential rounds (wave w adds after wave w-1's barrier).
    #pragma unroll
    for (int w = 0; w < 4; ++w) {
        if (wv == w) {
            #pragma unroll
            for (int t = 0; t < 32; ++t)
                #pragma unroll
                for (int r = 0; r < 4; ++r) {
                    int off = (quad * 4 + r) * K + t * 16 + l15;
                    if (w == 0) red[off] = acc[t][r];
                    else        red[off] += acc[t][r];
                }
        }
        __syncthreads();
    }

    // flush: coalesced native global atomics (consecutive tid -> consecutive addr)
    for (int i = tid; i < 16 * K; i += 256) {
        int dd = i >> 9, k = i & 511;
        unsafeAtomicAdd(&esum[(d0 + dd) * K + k], red[i]);
    }
    if (doCnt) {
        unsafeAtomicAdd(&enc[tid], (float)hist[tid]);
        unsafeAtomicAdd(&enc[tid + 256], (float)hist[tid + 256]);
    }
}

// ---------------------------------------------------------------------------
// k_final: scalar part only (ncs, n, loss). 1 block.
__global__ __launch_bounds__(512) void k_final(const float* __restrict__ enc,
                                               const float* __restrict__ cs_in,
                                               const float* __restrict__ lossAcc,
                                               float* __restrict__ out,
                                               float* __restrict__ nnOut) {
    __shared__ float red[512];
    int k = threadIdx.x;
    float ncs = fmaf(cs_in[k], 0.99f, 0.01f * enc[k]);
    red[k] = ncs;
    out[NCS_OFF + k] = ncs;
    __syncthreads();
    for (int s = 256; s > 0; s >>= 1) {
        if (k < s) red[k] += red[k + s];
        __syncthreads();
    }
    if (k == 0) {
        nnOut[0] = fmaxf(red[0], 1e-5f);
        out[LOSS_OFF] = lossAcc[0] * 1.25f / 16777216.0f;
    }
}

// k_final2: embedding update, fully parallel (128 blocks = one per d), coalesced.
__global__ __launch_bounds__(512) void k_final2(const float* __restrict__ esum,
                                                const float* __restrict__ eavg_in,
                                                const float* __restrict__ nnIn,
                                                float* __restrict__ out) {
    int d = blockIdx.x;
    int k = threadIdx.x;
    float nn = nnIn[0];
    float ncs = out[NCS_OFF + k];
    float cs = (ncs + 1e-5f) / (nn + (float)K * 1e-5f) * nn;
    float ea = fmaf(eavg_in[d * K + k], 0.99f, 0.01f * esum[d * K + k]);
    out[NEA_OFF + d * K + k] = ea;
    out[NEMB_OFF + d * K + k] = ea / cs;
}

// ---------------------------------------------------------------------------
extern "C" void kernel_launch(void* const* d_in, const int* in_sizes, int n_in,
                              void* d_out, int out_size, void* d_ws, size_t ws_size,
                              hipStream_t stream) {
    const float* z     = (const float*)d_in[0];
    const float* emb   = (const float*)d_in[1];
    const float* cs_in = (const float*)d_in[2];
    const float* eavg  = (const float*)d_in[3];
    float* out = (float*)d_out;
    float* wsF = (float*)d_ws;

    // E2 (512) + ENC (512) are contiguous: one memset
    hipMemsetAsync(wsF + WS_E2, 0, 1024 * sizeof(float), stream);
    hipMemsetAsync(wsF + WS_LOSS, 0, sizeof(float), stream);

    k_prep<<<256, 256, 0, stream>>>(emb, (f16*)(wsF + WS_EHI), (f16*)(wsF + WS_ELO),
                                    wsF + WS_E2);
    k_assign<<<NPOS / 64, 256, 0, stream>>>(z,
                                            (const f16*)(wsF + WS_EHI),
                                            (const f16*)(wsF + WS_ELO),
                                            wsF + WS_E2, out, wsF + WS_LOSS);
    // e_hiP/e_loP no longer needed: reclaim region as esum
    hipMemsetAsync(wsF + WS_ESUM, 0, 65536 * sizeof(float), stream);
    k_ema2<<<512, 256, 0, stream>>>(z, out, wsF + WS_ENC, wsF + WS_ESUM);
    k_final<<<1, 512, 0, stream>>>(wsF + WS_ENC, cs_in, wsF + WS_LOSS,
                                   out, wsF + WS_NN);
    k_final2<<<128, 512, 0, stream>>>(wsF + WS_ESUM, eavg, wsF + WS_NN, out);
}